// Round 2
// baseline (11976.371 us; speedup 1.0000x reference)
//
#include <hip/hip_runtime.h>
#include <hip/hip_fp16.h>
#include <stdint.h>

// ---------------------------------------------------------------------------
// SequentialEMGPoseLSTM: 2-layer LSTM (H=256, B=64, T=4096) + LeakyReLU+Linear
//
// R4 changes vs R3 (post-mortem: VGPR_Count=128 at 2 waves/SIMD means the
// 192 "pinned" weight regs live in AGPRs -> ~190 v_accvgpr_read per step
// doubled VALU issue; 74% busy on recurrent CUs matches dur exactly):
//  - Register demand cut below the 256/wave budget so weights are truly
//    VGPR-resident:
//    * layer0's x-dot offloaded: xw0 = Wih0*x_t precomputed per chunk by the
//      layer0 block prologue (chunk ch+1; chunk 0 bootstrapped at L==0 by
//      compute -> barrier (vmcnt drain) -> read back). Removes wx[16] regs
//      and 16 fdot2/step; both layers now share the identical lean step body.
//    * hh consumed via rolling 8-u32 sub-blocks (peak 8-12 regs, was 16).
//  - xw0/xw1 stored f16 (halves workspace so 4 rotating xw buffers fit and
//    Tc stays 256).
// ---------------------------------------------------------------------------

#define T_SEQ 4096
#define NB    64
#define HID   256
#define G4    1024
#define INCH  16
#define OC    20

typedef _Float16 h2v   __attribute__((ext_vector_type(2)));
typedef _Float16 f16x8 __attribute__((ext_vector_type(8)));
typedef float    f32x4 __attribute__((ext_vector_type(4)));

__device__ __forceinline__ float fdot2(uint32_t a, uint32_t b, float c) {
  return __builtin_amdgcn_fdot2(__builtin_bit_cast(h2v, a),
                                __builtin_bit_cast(h2v, b), c, false);
}
__device__ __forceinline__ float sigf(float x) {
  x = fminf(fmaxf(x, -30.f), 30.f);
  return 1.f / (1.f + __expf(-x));
}
__device__ __forceinline__ float tanhf_fast(float x) {
  x = fminf(fmaxf(x, -15.f), 15.f);
  float e = __expf(-2.f * x);
  return (1.f - e) / (1.f + e);
}
// Sum across the 4 slices of a quad (lanes differing in bits 0-1) on the
// VALU pipe: quad_perm(1,0,3,2)=0xB1 then quad_perm(2,3,0,1)=0x4E.
__device__ __forceinline__ float quad_sum(float a) {
  a += __int_as_float(
      __builtin_amdgcn_update_dpp(0, __float_as_int(a), 0xB1, 0xF, 0xF, true));
  a += __int_as_float(
      __builtin_amdgcn_update_dpp(0, __float_as_int(a), 0x4E, 0xF, 0xF, true));
  return a;
}

#define PIN(x) asm volatile("" : "+v"(x))

// Padded LDS layouts (all offsets 16B-aligned):
//  w   : 256 rows x 264 halves (rows 768..1023 of Whh). Row r at bank 4r%32.
//  hbuf: 2 x (4 slices x 72 halves). Slice s at bank offset 4s -> disjoint spans.
//  abuf: 2 x (8 chunks x 40 halves). Chunk ks at bank 20ks%32 -> all distinct.
struct SmemR {
  __half w[256 * 264];        // 135168 B
  uint32_t hbuf[2][144];      // 1152 B
  union {
    uint32_t xb[512 * 8];     // layer0 prologue: packed x pairs [tt][dp], Tc<=512
    struct {
      __half abuf[2][320];    // layer1: leaky(h2), padded chunks
      __half whd[20 * 264];   // head weights, padded rows
      float  bh[20];
    } h1;
  } u;
};
struct SmemG {
  __half a[128 * 40];
  __half b[64 * 40];
};
union Smem { SmemR r; SmemG g; };

struct Params {
  const float* x;
  const __half *wh0, *wh1, *wi0, *wi1, *whd;
  const float  *bs0, *bs1, *bhd;
  float *h0s, *c0s, *h1s, *c1s;
  __half* h1w; const __half* h1r;
  __half* xw1w; const __half* xw1r;  // layer1 input-contrib (GEMM role writes)
  __half* xw0w; const __half* xw0r;  // layer0 input-contrib (layer0 prologue)
  float* y;
  int L, Tc, nch;
};

// ---------------------------------------------------------------------------
// xw0[(tt*NB+b)*G4 + g] = (Wih0 row g) . x_t  (f16), for chunk cc, batch b.
// 512 threads: thread handles rows g=tid and g=tid+512. x staged in S.u.xb.
// ---------------------------------------------------------------------------
__device__ void compute_xw0(SmemR& S, int cc, const Params& P, int b,
                            __half* out) {
  const int tid = threadIdx.x;
  const int Tc  = P.Tc;
  const int t0  = cc * Tc;
  for (int i = tid; i < Tc * 8; i += 512) {
    int dp = i / Tc, tt = i - dp * Tc;
    float v0 = P.x[(b * INCH + 2 * dp) * T_SEQ + t0 + tt];
    float v1 = P.x[(b * INCH + 2 * dp + 1) * T_SEQ + t0 + tt];
    uint32_t pv = (uint32_t)__half_as_ushort(__float2half(v0)) |
                  ((uint32_t)__half_as_ushort(__float2half(v1)) << 16);
    S.u.xb[tt * 8 + dp] = pv;
  }
  __syncthreads();
  uint32_t w0[8], w1[8];
  {
    const uint4* p0 = (const uint4*)(P.wi0 + tid * INCH);
    const uint4* p1 = (const uint4*)(P.wi0 + (tid + 512) * INCH);
    uint4 a0 = p0[0], a1 = p0[1], b0 = p1[0], b1 = p1[1];
    w0[0] = a0.x; w0[1] = a0.y; w0[2] = a0.z; w0[3] = a0.w;
    w0[4] = a1.x; w0[5] = a1.y; w0[6] = a1.z; w0[7] = a1.w;
    w1[0] = b0.x; w1[1] = b0.y; w1[2] = b0.z; w1[3] = b0.w;
    w1[4] = b1.x; w1[5] = b1.y; w1[6] = b1.z; w1[7] = b1.w;
  }
  for (int tt = 0; tt < Tc; ++tt) {
    uint32_t xv[8];
    const uint4* xp = (const uint4*)&S.u.xb[tt * 8];
    uint4 v0 = xp[0], v1 = xp[1];
    xv[0] = v0.x; xv[1] = v0.y; xv[2] = v0.z; xv[3] = v0.w;
    xv[4] = v1.x; xv[5] = v1.y; xv[6] = v1.z; xv[7] = v1.w;
    float a0 = 0.f, a1 = 0.f;
#pragma unroll
    for (int q = 0; q < 8; ++q) {
      a0 = fdot2(w0[q], xv[q], a0);
      a1 = fdot2(w1[q], xv[q], a1);
    }
    __half* o = out + (size_t)(tt * NB + b) * G4;
    o[tid]       = __float2half(a0);
    o[tid + 512] = __float2half(a1);
  }
  __syncthreads();  // xb safe to reuse; stores drained by barrier's vmcnt(0)
}

// ---------------------------------------------------------------------------
// Recurrent role: one block == one batch chain. 512 threads.
// slice = tid&3 covers k in [64*slice, 64*slice+64); rg = tid>>2 (0..127).
// Thread handles gate rows r = rg + 128*j, j=0..7 (j<6 reg, j>=6 LDS).
// Row rg+128j: j even -> gate (j/2) of channel rg; j odd -> of channel rg+128.
// Owners: slice0 -> channel rg, slice1 -> channel rg+128.
// ---------------------------------------------------------------------------
template <int LAYER>
__device__ void role_rec(SmemR& S, int ch, const Params& P, int b) {
  if (ch < 0 || ch >= P.nch) return;
  const int tid   = threadIdx.x;
  const int slice = tid & 3;
  const int rg    = tid >> 2;
  const int Tc    = P.Tc;
  const __half* whh = (LAYER == 0) ? P.wh0 : P.wh1;

  // Stage LDS-resident weight rows 768..1023 into padded layout.
  for (int i = tid; i < 8192; i += 512) {
    int R = i >> 5, oct = i & 31;
    *(uint4*)&S.w[R * 264 + oct * 8] =
        *((const uint4*)(whh + (768 + R) * 256) + oct);
  }
  const int t0 = ch * Tc;
  if (LAYER == 0) {
    // Prologue: produce xw0 for chunk ch+1 (and chunk 0 at the start).
    if (ch == 0) compute_xw0(S, 0, P, b, P.xw0w == nullptr ? nullptr : (__half*)P.xw0r);
    if (ch + 1 < P.nch) compute_xw0(S, ch + 1, P, b, P.xw0w);
  } else {
    for (int i = tid; i < OC * 256; i += 512) {
      int o = i >> 8, k = i & 255;
      S.u.h1.whd[o * 264 + k] = P.whd[i];
    }
    if (tid < OC) S.u.h1.bh[tid] = P.bhd[tid];
  }

  // Register-resident weights: rows j=0..5, 64 halves each (32 packed u32).
  uint32_t wr[6][32];
#pragma unroll
  for (int j = 0; j < 6; j++) {
    const uint4* p = (const uint4*)(whh + (rg + 128 * j) * 256 + slice * 64);
#pragma unroll
    for (int q = 0; q < 8; q++) {
      uint4 v = p[q];
      wr[j][4 * q] = v.x; wr[j][4 * q + 1] = v.y;
      wr[j][4 * q + 2] = v.z; wr[j][4 * q + 3] = v.w;
    }
  }
#pragma unroll
  for (int j = 0; j < 6; j++)
#pragma unroll
    for (int q = 0; q < 32; q++) PIN(wr[j][q]);

  // Owner state: slice0 -> channel rg; slice1 -> channel rg+128 (fp32 h,c).
  const bool own = (slice < 2);
  const int chn = rg + ((slice & 1) << 7);
  float* hs = (LAYER == 0) ? P.h0s : P.h1s;
  float* cs = (LAYER == 0) ? P.c0s : P.c1s;
  float bs4[4] = {0.f, 0.f, 0.f, 0.f};
  float hO = 0.f, cO = 0.f;
  if (own) {
    const float* bsg = (LAYER == 0) ? P.bs0 : P.bs1;
#pragma unroll
    for (int k = 0; k < 4; k++) bs4[k] = bsg[chn + 256 * k];
    if (ch != 0) { hO = hs[b * 256 + chn]; cO = cs[b * 256 + chn]; }
    ((__half*)S.hbuf[0])[(chn >> 6) * 72 + (chn & 63)] = __float2half(hO);
  }
  const __half* xp = nullptr;
  if (own) xp = ((LAYER == 0) ? P.xw0r : P.xw1r) + (size_t)b * G4 + chn;
  __syncthreads();

  const __half* hbA = (const __half*)S.hbuf[0] + slice * 72;
  const __half* hbB = (const __half*)S.hbuf[1] + slice * 72;
  const __half* wbase6 = &S.w[rg * 264 + slice * 64];
  const __half* wbase7 = &S.w[(128 + rg) * 264 + slice * 64];
  __half hprev = __float2half(0.f);

  for (int tt = 0; tt < Tc; ++tt) {
    // ---- post-barrier zone: global ops retire under this step's compute.
    if (LAYER == 0 && own && tt > 0)
      P.h1w[(size_t)((tt - 1) * NB + b) * 256 + chn] = hprev;
    float xwv[4] = {0.f, 0.f, 0.f, 0.f};
    if (own) {
      const __half* q = xp + (size_t)tt * (NB * G4);
      xwv[0] = __half2float(q[0]);
      xwv[1] = __half2float(q[256]);
      xwv[2] = __half2float(q[512]);
      xwv[3] = __half2float(q[768]);
    }

    const __half* hb = (tt & 1) ? hbB : hbA;
    const uint4* hp = (const uint4*)hb;
    float acc[8];
#pragma unroll
    for (int j = 0; j < 8; j++) acc[j] = 0.f;

    // 4 sub-blocks of 16 halves: rolling hh keeps only 8 u32 live.
#pragma unroll
    for (int sb = 0; sb < 4; ++sb) {
      uint32_t hh[8];
      {
        uint4 v0 = hp[2 * sb], v1 = hp[2 * sb + 1];
        hh[0] = v0.x; hh[1] = v0.y; hh[2] = v0.z; hh[3] = v0.w;
        hh[4] = v1.x; hh[5] = v1.y; hh[6] = v1.z; hh[7] = v1.w;
      }
#pragma unroll
      for (int j = 0; j < 6; ++j) {
        float a = acc[j];
#pragma unroll
        for (int q = 0; q < 8; ++q) a = fdot2(wr[j][8 * sb + q], hh[q], a);
        acc[j] = a;
      }
      {
        const uint4* wp = (const uint4*)(wbase6 + sb * 16);
        uint4 w0 = wp[0], w1 = wp[1];
        float a = acc[6];
        a = fdot2(w0.x, hh[0], a); a = fdot2(w0.y, hh[1], a);
        a = fdot2(w0.z, hh[2], a); a = fdot2(w0.w, hh[3], a);
        a = fdot2(w1.x, hh[4], a); a = fdot2(w1.y, hh[5], a);
        a = fdot2(w1.z, hh[6], a); a = fdot2(w1.w, hh[7], a);
        acc[6] = a;
      }
      {
        const uint4* wp = (const uint4*)(wbase7 + sb * 16);
        uint4 w0 = wp[0], w1 = wp[1];
        float a = acc[7];
        a = fdot2(w0.x, hh[0], a); a = fdot2(w0.y, hh[1], a);
        a = fdot2(w0.z, hh[2], a); a = fdot2(w0.w, hh[3], a);
        a = fdot2(w1.x, hh[4], a); a = fdot2(w1.y, hh[5], a);
        a = fdot2(w1.z, hh[6], a); a = fdot2(w1.w, hh[7], a);
        acc[7] = a;
      }
    }
    // Reduce across the 4 slices on the VALU pipe (DPP).
#pragma unroll
    for (int j = 0; j < 8; j++) acc[j] = quad_sum(acc[j]);

    if (own) {
      const int o = slice & 1;  // 0 -> channel rg (even j), 1 -> rg+128 (odd j)
      float gi = acc[0 + o] + bs4[0] + xwv[0];
      float gf = acc[2 + o] + bs4[1] + xwv[1];
      float gg = acc[4 + o] + bs4[2] + xwv[2];
      float go = acc[6 + o] + bs4[3] + xwv[3];
      float iv = sigf(gi), fv = sigf(gf);
      float gv = tanhf_fast(gg), ov = sigf(go);
      cO = fv * cO + iv * gv;
      hO = ov * tanhf_fast(cO);
      __half h16 = __float2half(hO);
      ((__half*)S.hbuf[(tt + 1) & 1])[(chn >> 6) * 72 + (chn & 63)] = h16;
      if (LAYER == 0) {
        hprev = h16;  // stored at top of next iteration (post-barrier)
      } else {
        float av = hO > 0.f ? hO : 0.01f * hO;
        S.u.h1.abuf[tt & 1][(chn >> 5) * 40 + (chn & 31)] = __float2half(av);
      }
    }
    __syncthreads();

    // Head (layer1): 20 outputs x 8 lanes x 32 k. Reads abuf[tt&1] written
    // before the barrier; next overwrite of that buffer is 2 steps away and
    // gated by the intervening barrier.
    if (LAYER == 1 && tid < OC * 8) {
      int o = tid >> 3, ks = tid & 7;
      const uint4* wp = (const uint4*)&S.u.h1.whd[o * 264 + ks * 32];
      const uint4* ap = (const uint4*)&S.u.h1.abuf[tt & 1][ks * 40];
      float a = 0.f;
#pragma unroll
      for (int q = 0; q < 4; q++) {
        uint4 w4 = wp[q];
        uint4 a4 = ap[q];
        a = fdot2(w4.x, a4.x, a);
        a = fdot2(w4.y, a4.y, a);
        a = fdot2(w4.z, a4.z, a);
        a = fdot2(w4.w, a4.w, a);
      }
      a += __shfl_xor(a, 1);
      a += __shfl_xor(a, 2);
      a += __shfl_xor(a, 4);
      if (ks == 0) P.y[(b * OC + o) * T_SEQ + t0 + tt] = a + S.u.h1.bh[o];
    }
  }
  if (own) {
    if (LAYER == 0)
      P.h1w[(size_t)((Tc - 1) * NB + b) * 256 + chn] = hprev;
    hs[b * 256 + chn] = hO;
    cs[b * 256 + chn] = cO;
  }
}

// ---------------------------------------------------------------------------
// GEMM role: xw1[tb, g] = sum_k h1[tb,k] * Wih1[g,k], f16 MFMA, f16 out.
// ---------------------------------------------------------------------------
__device__ void role_gemm(SmemG& S, int chG, const Params& P) {
  if (chG < 0 || chG >= P.nch) return;
  const int bid = blockIdx.x - 128;
  const int nt = bid & 15, mt = bid >> 4;
  const int tb0 = mt * 128, g0 = nt * 64;
  const int tid = threadIdx.x, lane = tid & 63, w = tid >> 6;
  const int wm = w & 3, wn = w >> 2;

  f32x4 cacc[2][2] = {};
  for (int kk = 0; kk < 256; kk += 32) {
    __syncthreads();
    {
      int row = tid >> 2, q = tid & 3;
      const uint4* src = (const uint4*)(P.h1r + (tb0 + row) * 256 + kk + q * 8);
      *(uint4*)&S.a[row * 40 + q * 8] = *src;
    }
    if (tid < 256) {
      int row = tid >> 2, q = tid & 3;
      const uint4* src = (const uint4*)(P.wi1 + (g0 + row) * 256 + kk + q * 8);
      *(uint4*)&S.b[row * 40 + q * 8] = *src;
    }
    __syncthreads();
    f16x8 af[2], bf[2];
#pragma unroll
    for (int mi = 0; mi < 2; mi++)
      af[mi] = *(const f16x8*)&S.a[(wm * 32 + mi * 16 + (lane & 15)) * 40 + (lane >> 4) * 8];
#pragma unroll
    for (int ni = 0; ni < 2; ni++)
      bf[ni] = *(const f16x8*)&S.b[(wn * 32 + ni * 16 + (lane & 15)) * 40 + (lane >> 4) * 8];
#pragma unroll
    for (int mi = 0; mi < 2; mi++)
#pragma unroll
      for (int ni = 0; ni < 2; ni++)
        cacc[mi][ni] = __builtin_amdgcn_mfma_f32_16x16x32_f16(af[mi], bf[ni], cacc[mi][ni], 0, 0, 0);
  }
#pragma unroll
  for (int mi = 0; mi < 2; mi++)
#pragma unroll
    for (int ni = 0; ni < 2; ni++) {
      int m = wm * 32 + mi * 16 + (lane >> 4) * 4;
      int n = g0 + wn * 32 + ni * 16 + (lane & 15);
#pragma unroll
      for (int r = 0; r < 4; r++)
        P.xw1w[(size_t)(tb0 + m + r) * G4 + n] = __float2half(cacc[mi][ni][r]);
    }
}

__global__ __launch_bounds__(512)
__attribute__((amdgpu_waves_per_eu(2, 2)))
void fused_kernel(Params P) {
  __shared__ Smem S;
  int bid = blockIdx.x;
  if (bid < 64)        role_rec<0>(S.r, P.L, P, bid);
  else if (bid < 128)  role_rec<1>(S.r, P.L - 2, P, bid - 64);
  else                 role_gemm(S.g, P.L - 1, P);
}

// ---------------------------------------------------------------------------
__global__ void prep_kernel(const float* Wih0, const float* Whh0,
                            const float* bih0, const float* bhh0,
                            const float* Wih1, const float* Whh1,
                            const float* bih1, const float* bhh1,
                            const float* Whead, const float* bhead,
                            __half* wh0, __half* wh1, __half* wi1, __half* wi0,
                            __half* whd, float* bs0, float* bs1, float* bhd) {
  int i = blockIdx.x * blockDim.x + threadIdx.x;
  if (i < G4 * HID) {
    wh0[i] = __float2half(Whh0[i]);
    wh1[i] = __float2half(Whh1[i]);
    wi1[i] = __float2half(Wih1[i]);
  }
  if (i < G4 * INCH) wi0[i] = __float2half(Wih0[i]);
  if (i < OC * HID)  whd[i] = __float2half(Whead[i]);
  if (i < G4) { bs0[i] = bih0[i] + bhh0[i]; bs1[i] = bih1[i] + bhh1[i]; }
  if (i < OC) bhd[i] = bhead[i];
}

// ---------------------------------------------------------------------------
extern "C" void kernel_launch(void* const* d_in, const int* in_sizes, int n_in,
                              void* d_out, int out_size, void* d_ws, size_t ws_size,
                              hipStream_t stream) {
  const float* x     = (const float*)d_in[0];
  const float* Wih0  = (const float*)d_in[1];
  const float* Whh0  = (const float*)d_in[2];
  const float* bih0  = (const float*)d_in[3];
  const float* bhh0  = (const float*)d_in[4];
  const float* Wih1  = (const float*)d_in[5];
  const float* Whh1  = (const float*)d_in[6];
  const float* bih1  = (const float*)d_in[7];
  const float* bhh1  = (const float*)d_in[8];
  const float* Whead = (const float*)d_in[9];
  const float* bhead = (const float*)d_in[10];
  float* y = (float*)d_out;

  char* ws = (char*)d_ws;
  size_t cur = 0;
  auto alloc = [&](size_t sz) -> char* {
    char* p = ws + cur;
    cur = (cur + sz + 255) & ~(size_t)255;
    return p;
  };
  __half* wh0 = (__half*)alloc(G4 * HID * 2);
  __half* wh1 = (__half*)alloc(G4 * HID * 2);
  __half* wi1 = (__half*)alloc(G4 * HID * 2);
  __half* wi0 = (__half*)alloc(G4 * INCH * 2);
  __half* whd = (__half*)alloc(OC * HID * 2);
  float* bs0 = (float*)alloc(G4 * 4);
  float* bs1 = (float*)alloc(G4 * 4);
  float* bhd = (float*)alloc(OC * 4);
  float* h0s = (float*)alloc(NB * HID * 4);
  float* c0s = (float*)alloc(NB * HID * 4);
  float* h1s = (float*)alloc(NB * HID * 4);
  float* c1s = (float*)alloc(NB * HID * 4);
  size_t fixed = cur;

  int Tc = 512;
  while (Tc > 64) {
    size_t need = fixed + 2 * ((size_t)Tc * NB * HID * 2 + 512) +
                  4 * ((size_t)Tc * NB * G4 * 2 + 512);
    if (need <= ws_size) break;
    Tc >>= 1;
  }
  __half* h1buf[2];
  __half* xw1buf[2];
  __half* xw0buf[2];
  h1buf[0]  = (__half*)alloc((size_t)Tc * NB * HID * 2);
  h1buf[1]  = (__half*)alloc((size_t)Tc * NB * HID * 2);
  xw1buf[0] = (__half*)alloc((size_t)Tc * NB * G4 * 2);
  xw1buf[1] = (__half*)alloc((size_t)Tc * NB * G4 * 2);
  xw0buf[0] = (__half*)alloc((size_t)Tc * NB * G4 * 2);
  xw0buf[1] = (__half*)alloc((size_t)Tc * NB * G4 * 2);

  const int nch = T_SEQ / Tc;

  prep_kernel<<<(G4 * HID + 255) / 256, 256, 0, stream>>>(
      Wih0, Whh0, bih0, bhh0, Wih1, Whh1, bih1, bhh1, Whead, bhead,
      wh0, wh1, wi1, wi0, whd, bs0, bs1, bhd);

  const int ngemm = Tc * 8;
  for (int L = 0; L < nch + 2; ++L) {
    Params P;
    P.x = x;
    P.wh0 = wh0; P.wh1 = wh1; P.wi0 = wi0; P.wi1 = wi1; P.whd = whd;
    P.bs0 = bs0; P.bs1 = bs1; P.bhd = bhd;
    P.h0s = h0s; P.c0s = c0s; P.h1s = h1s; P.c1s = c1s;
    P.h1w = h1buf[L & 1];
    P.h1r = h1buf[(L + 1) & 1];
    P.xw1w = xw1buf[(L + 1) & 1];
    P.xw1r = xw1buf[L & 1];
    P.xw0w = xw0buf[(L + 1) & 1];
    P.xw0r = xw0buf[L & 1];
    P.y = y;
    P.L = L; P.Tc = Tc; P.nch = nch;
    fused_kernel<<<128 + ngemm, 512, 0, stream>>>(P);
  }
}